// Round 14
// baseline (252.735 us; speedup 1.0000x reference)
//
#include <hip/hip_runtime.h>

#define N_NODES 100000
#define N_EDGES 1600000
#define MPAD    100096   /* 782 * 128 = 1564 * 64 */
#define MT64    1564

#define NB      391      /* ceil(100000/256) buckets of 256 nodes */
#define CH      8192     /* edges per phase-A block */
#define NBLK_A  196      /* ceil(1600000/8192) */

typedef __attribute__((ext_vector_type(8))) short short8;
typedef __attribute__((ext_vector_type(4))) float f32x4;

static __device__ __forceinline__ unsigned short f2bf(float f) {
  unsigned u = __builtin_bit_cast(unsigned, f);
  u += 0x7fffu + ((u >> 16) & 1u);     // round-to-nearest-even
  return (unsigned short)(u >> 16);
}
static __device__ __forceinline__ float bf2f(unsigned short s) {
  unsigned u = ((unsigned)s) << 16;
  return __builtin_bit_cast(float, u);
}

// ---------------- CSR build: two-level LDS counting sort ----------------

__global__ __launch_bounds__(256) void k_bhist(const int* __restrict__ row,
                                               int* __restrict__ Hc) {
  __shared__ int hist[NB];
  int b = blockIdx.x, t = threadIdx.x;
  for (int j = t; j < NB; j += 256) hist[j] = 0;
  __syncthreads();
  int base = b * CH;
  #pragma unroll
  for (int k = 0; k < 8; ++k) {
    int i = base + k * 1024 + t * 4;
    if (i < N_EDGES) {
      int4 r = *(const int4*)(row + i);
      atomicAdd(&hist[r.x >> 8], 1);
      atomicAdd(&hist[r.y >> 8], 1);
      atomicAdd(&hist[r.z >> 8], 1);
      atomicAdd(&hist[r.w >> 8], 1);
    }
  }
  __syncthreads();
  for (int j = t; j < NB; j += 256) Hc[j * NBLK_A + b] = hist[j];
}

__global__ __launch_bounds__(512) void k_bscan(const int* __restrict__ Hc,
                                               int* __restrict__ Boff) {
  int t = threadIdx.x;
  int total = 0;
  if (t < NB) {
    const int* p = Hc + t * NBLK_A;
    for (int i = 0; i < NBLK_A; i += 4) {
      int4 v = *(const int4*)(p + i);
      total += v.x + v.y + v.z + v.w;
    }
  }
  int lane = t & 63, w = t >> 6;
  int incl = total;
  #pragma unroll
  for (int off = 1; off < 64; off <<= 1) {
    int n = __shfl_up(incl, off, 64);
    if (lane >= off) incl += n;
  }
  __shared__ int ws[8];
  if (lane == 63) ws[w] = incl;
  __syncthreads();
  int wo = 0;
  for (int ww = 0; ww < w; ++ww) wo += ws[ww];
  int excl = wo + incl - total;
  if (t < NB) Boff[t] = excl;
  if (t == NB - 1) Boff[NB] = excl + total;
}

__global__ __launch_bounds__(64) void k_bexp(const int* __restrict__ Hc,
                                             const int* __restrict__ Boff,
                                             int* __restrict__ G) {
  int b = blockIdx.x, l = threadIdx.x;
  int run = Boff[b];
  const int* p = Hc + b * NBLK_A;
  for (int c = 0; c < NBLK_A; c += 64) {
    int idx = c + l;
    int v = (idx < NBLK_A) ? p[idx] : 0;
    int incl = v;
    #pragma unroll
    for (int off = 1; off < 64; off <<= 1) {
      int n = __shfl_up(incl, off, 64);
      if (l >= off) incl += n;
    }
    if (idx < NBLK_A) G[b * NBLK_A + idx] = run + incl - v;
    run += __shfl(incl, 63, 64);
  }
}

__global__ __launch_bounds__(256) void k_bscat(const int* __restrict__ row,
                                               const int* __restrict__ col,
                                               const int* __restrict__ G,
                                               unsigned* __restrict__ tmp) {
  __shared__ int cur[NB];
  int b = blockIdx.x, t = threadIdx.x;
  for (int j = t; j < NB; j += 256) cur[j] = G[j * NBLK_A + b];
  __syncthreads();
  int base = b * CH;
  #pragma unroll
  for (int k = 0; k < 8; ++k) {
    int i = base + k * 1024 + t * 4;
    if (i < N_EDGES) {
      int4 r = *(const int4*)(row + i);
      int4 c = *(const int4*)(col + i);
      int p0 = atomicAdd(&cur[r.x >> 8], 1);
      tmp[p0] = (unsigned)c.x | ((unsigned)(r.x & 255) << 24);
      int p1 = atomicAdd(&cur[r.y >> 8], 1);
      tmp[p1] = (unsigned)c.y | ((unsigned)(r.y & 255) << 24);
      int p2 = atomicAdd(&cur[r.z >> 8], 1);
      tmp[p2] = (unsigned)c.z | ((unsigned)(r.z & 255) << 24);
      int p3 = atomicAdd(&cur[r.w >> 8], 1);
      tmp[p3] = (unsigned)c.w | ((unsigned)(r.w & 255) << 24);
    }
  }
}

__global__ __launch_bounds__(256) void k_bsort(const unsigned* __restrict__ tmp,
                                               const int* __restrict__ Boff,
                                               int* __restrict__ rp,
                                               int* __restrict__ cs) {
  __shared__ int hist[256];
  __shared__ int wsum[4];
  int b = blockIdx.x, t = threadIdx.x;
  int s = Boff[b], e = Boff[b + 1];
  hist[t] = 0;
  __syncthreads();
  for (int i = s + t; i < e; i += 256) atomicAdd(&hist[tmp[i] >> 24], 1);
  __syncthreads();
  int v = hist[t];
  int lane = t & 63, w = t >> 6;
  int incl = v;
  #pragma unroll
  for (int off = 1; off < 64; off <<= 1) {
    int n = __shfl_up(incl, off, 64);
    if (lane >= off) incl += n;
  }
  if (lane == 63) wsum[w] = incl;
  __syncthreads();
  int wo = 0;
  for (int ww = 0; ww < w; ++ww) wo += wsum[ww];
  int excl = s + wo + incl - v;
  int node = (b << 8) + t;
  if (node < N_NODES) rp[node] = excl;
  __syncthreads();
  hist[t] = excl;    // reuse as cursor
  __syncthreads();
  for (int i = s + t; i < e; i += 256) {
    unsigned u = tmp[i];
    int pos = atomicAdd(&hist[u >> 24], 1);
    cs[pos] = (int)(u & 0xFFFFFFu);
  }
  if (b == 0 && t == 0) rp[N_NODES] = N_EDGES;
}

// ---------------- prep: weight pack + x f32->bf16 (fused launch) ----------------

__global__ __launch_bounds__(256) void k_prep(const float* __restrict__ x,
                                              const float* __restrict__ Wl1,
                                              const float* __restrict__ Wr1,
                                              const float* __restrict__ Wl2,
                                              const float* __restrict__ Wr2,
                                              short* __restrict__ Bp1,
                                              short* __restrict__ Bp2,
                                              short* __restrict__ Acat) {
  if (blockIdx.x < 512) {
    int id = blockIdx.x * 256 + threadIdx.x;
    bool second = id >= 65536;
    int lid = id & 65535;
    int j = lid & 7;
    int lane = (lid >> 3) & 63;
    int blk = lid >> 9;
    int nb = blk & 15;
    int kk = blk >> 4;
    int k = kk * 32 + (lane >> 4) * 8 + j;
    int c = nb * 16 + (lane & 15);
    float v;
    if (!second) v = (k < 128) ? Wl1[k * 256 + c] : Wr1[(k - 128) * 256 + c];
    else         v = (c < 128) ? Wl2[k * 128 + c] : Wr2[k * 128 + (c - 128)];
    (second ? Bp2 : Bp1)[lid] = (short)f2bf(v);
  } else {
    int id = (blockIdx.x - 512) * 256 + threadIdx.x;
    if (id >= N_NODES * 32) return;
    int node = id >> 5, c4 = id & 31;
    float4 v = *(const float4*)(x + (size_t)node * 128 + c4 * 4);
    uint2 u;
    u.x = (unsigned)f2bf(v.x) | ((unsigned)f2bf(v.y) << 16);
    u.y = (unsigned)f2bf(v.z) | ((unsigned)f2bf(v.w) << 16);
    *(uint2*)(Acat + (size_t)node * 256 + 128 + c4 * 4) = u;
  }
}

// ---------------- aggregation (R7 version: measured 64.4 us) ----------------

template <bool RESID, int GOFF>
__global__ __launch_bounds__(256) void k_agg(const int* __restrict__ rp,
                                             const int* __restrict__ cs,
                                             const short* __restrict__ src,
                                             short* __restrict__ dst_bf,
                                             float* __restrict__ dst_f32) {
  const int t = __builtin_amdgcn_readfirstlane(blockIdx.x * 4 + (threadIdx.x >> 6));
  if (t >= N_NODES) return;
  const int lane = threadIdx.x & 63;
  const int s = rp[t], e = rp[t + 1];
  const int d = e - s;
  float a0 = 0.f, a1 = 0.f;
  const short* gb = src + GOFF + 2 * lane;
  if (d > 0) {
    const int last = e - 1;
    const int rounds = (d + 15) >> 4;
    for (int r = 0; r < rounds; ++r) {
      int base = s + (r << 4);
      unsigned u[16];
      #pragma unroll
      for (int q = 0; q < 16; ++q) {
        int j = base + q;
        j = (j < last) ? j : last;                       // wave-uniform clamp
        u[q] = *(const unsigned*)(gb + (size_t)cs[j] * 256);
      }
      #pragma unroll
      for (int q = 0; q < 16; ++q) {
        a0 += bf2f((unsigned short)u[q]);
        a1 += bf2f((unsigned short)(u[q] >> 16));
      }
    }
    const int over = (rounds << 4) - d;
    if (over) {
      unsigned ul = *(const unsigned*)(gb + (size_t)cs[last] * 256);
      float c = (float)over;
      a0 -= c * bf2f((unsigned short)ul);
      a1 -= c * bf2f((unsigned short)(ul >> 16));
    }
  }
  if (RESID) {
    unsigned r = *(const unsigned*)(src + (size_t)t * 256 + 128 + 2 * lane);
    a0 += bf2f((unsigned short)r);
    a1 += bf2f((unsigned short)(r >> 16));
    float2 o = {a0, a1};
    *(float2*)(dst_f32 + (size_t)t * 128 + 2 * lane) = o;
  } else {
    *(unsigned*)(dst_bf + (size_t)t * 256 + 2 * lane) =
        (unsigned)f2bf(a0) | ((unsigned)f2bf(a1) << 16);
  }
}

// ---------------- fused double-GEMM (64-row tiles for occupancy) ----------------

// Per 64-row tile: h = relu(Acat@Bp1 + bl1) staged in 32 KB LDS (bf16,
// XOR-swizzled idx ^ ((row&7)<<3)), then P = h@Bp2 (+bl2 on cols 128..255),
// written via LDS full-line stores. 256 threads = 4 waves, wave w = 64-col
// strip. 32 KB LDS + 116 VGPR -> ~4 blocks/CU (~50% occ), grid 1564:
// barrier stalls overlap with other resident blocks' MFMA.
__global__ __launch_bounds__(256) void k_gemm2(const short* __restrict__ A,
                                               const short* __restrict__ Bp1,
                                               const float* __restrict__ bl1,
                                               const short* __restrict__ Bp2,
                                               const float* __restrict__ bl2,
                                               short* __restrict__ P) {
  __shared__ short hb[64 * 256];           // 32 KB
  const int rt = blockIdx.x;
  const int lane = threadIdx.x & 63;
  const int wave = threadIdx.x >> 6;       // 0..3
  const int colbase = wave * 64;
  const int row0 = rt * 64;
  const int arow = lane & 15;
  const int kgrp = lane >> 4;
  const int ccol = lane & 15;
  const int crow = (lane >> 4) * 4;

  f32x4 acc[4][4];
  const f32x4 zero = {0.f, 0.f, 0.f, 0.f};
  #pragma unroll
  for (int a = 0; a < 4; ++a)
    #pragma unroll
    for (int b = 0; b < 4; ++b) acc[a][b] = zero;

  // ---- GEMM1: h = A @ Bp1 ----
  const short* Bbase1 = Bp1 + (size_t)lane * 8;
  for (int kk = 0; kk < 8; ++kk) {
    short8 af[4], bfr[4];
    const int kb = kk * 32 + kgrp * 8;
    #pragma unroll
    for (int mi = 0; mi < 4; ++mi)
      af[mi] = *(const short8*)(A + (size_t)(row0 + mi * 16 + arow) * 256 + kb);
    #pragma unroll
    for (int ni = 0; ni < 4; ++ni) {
      int nb = wave * 4 + ni;
      bfr[ni] = *(const short8*)(Bbase1 + ((size_t)(kk * 16 + nb) << 9));
    }
    #pragma unroll
    for (int mi = 0; mi < 4; ++mi)
      #pragma unroll
      for (int ni = 0; ni < 4; ++ni)
        acc[mi][ni] = __builtin_amdgcn_mfma_f32_16x16x32_bf16(af[mi], bfr[ni],
                                                              acc[mi][ni], 0, 0, 0);
  }

  // bias + relu -> swizzled LDS bf16
  #pragma unroll
  for (int ni = 0; ni < 4; ++ni) {
    const int colg = colbase + ni * 16 + ccol;
    const float bv = bl1[colg];
    #pragma unroll
    for (int mi = 0; mi < 4; ++mi) {
      #pragma unroll
      for (int j = 0; j < 4; ++j) {
        const int lrow = mi * 16 + crow + j;
        float v = fmaxf(acc[mi][ni][j] + bv, 0.0f);
        hb[(lrow * 256 + colg) ^ ((lrow & 7) << 3)] = (short)f2bf(v);
      }
    }
  }
  __syncthreads();

  // ---- GEMM2: P = h @ Bp2 ----
  #pragma unroll
  for (int a = 0; a < 4; ++a)
    #pragma unroll
    for (int b = 0; b < 4; ++b) acc[a][b] = zero;
  const short* Bbase2 = Bp2 + (size_t)lane * 8;
  for (int kk = 0; kk < 8; ++kk) {
    short8 af[4], bfr[4];
    const int kb = kk * 32 + kgrp * 8;
    #pragma unroll
    for (int mi = 0; mi < 4; ++mi) {
      const int lrow = mi * 16 + arow;
      af[mi] = *(const short8*)&hb[(lrow * 256 + kb) ^ ((lrow & 7) << 3)];
    }
    #pragma unroll
    for (int ni = 0; ni < 4; ++ni) {
      int nb = wave * 4 + ni;
      bfr[ni] = *(const short8*)(Bbase2 + ((size_t)(kk * 16 + nb) << 9));
    }
    #pragma unroll
    for (int mi = 0; mi < 4; ++mi)
      #pragma unroll
      for (int ni = 0; ni < 4; ++ni)
        acc[mi][ni] = __builtin_amdgcn_mfma_f32_16x16x32_bf16(af[mi], bfr[ni],
                                                              acc[mi][ni], 0, 0, 0);
  }
  __syncthreads();   // everyone done reading h before overwrite

  // bias2 (right half only) -> swizzled LDS bf16
  #pragma unroll
  for (int ni = 0; ni < 4; ++ni) {
    const int colg = colbase + ni * 16 + ccol;
    const float bv = (colg < 128) ? 0.f : bl2[colg - 128];
    #pragma unroll
    for (int mi = 0; mi < 4; ++mi) {
      #pragma unroll
      for (int j = 0; j < 4; ++j) {
        const int lrow = mi * 16 + crow + j;
        float v = acc[mi][ni][j] + bv;
        hb[(lrow * 256 + colg) ^ ((lrow & 7) << 3)] = (short)f2bf(v);
      }
    }
  }
  __syncthreads();

  // cooperative full-line store: 32 groups x 8 shorts = one 512 B row
  const int grp = threadIdx.x & 31;
  const int rb = threadIdx.x >> 5;         // 0..7
  #pragma unroll
  for (int pp = 0; pp < 8; ++pp) {
    const int r = pp * 8 + rb;
    uint4 v4 = *(const uint4*)&hb[(r * 256 + grp * 8) ^ ((r & 7) << 3)];
    *(uint4*)(P + (size_t)(row0 + r) * 256 + grp * 8) = v4;
  }
}

extern "C" void kernel_launch(void* const* d_in, const int* in_sizes, int n_in,
                              void* d_out, int out_size, void* d_ws, size_t ws_size,
                              hipStream_t stream) {
  const float* x   = (const float*)d_in[0];
  const int*   row = (const int*)d_in[1];
  const int*   col = (const int*)d_in[2];
  const float* Wl1 = (const float*)d_in[3];
  const float* bl1 = (const float*)d_in[4];
  const float* Wr1 = (const float*)d_in[5];
  const float* Wl2 = (const float*)d_in[6];
  const float* bl2 = (const float*)d_in[7];
  const float* Wr2 = (const float*)d_in[8];
  float* out = (float*)d_out;

  char* w = (char*)d_ws;
  auto alloc = [&](size_t bytes) {
    char* p = w;
    w += (bytes + 255) & ~(size_t)255;
    return p;
  };
  short* Acat = (short*)alloc((size_t)MPAD * 256 * 2);  // [agg_x_bf16 | x_bf16]
  short* P    = (short*)alloc((size_t)MPAD * 256 * 2);  // [h@Wl2 | h@Wr2+bl2], bf16
  short* Bp1  = (short*)alloc(65536 * 2);               // [Wl1;Wr1] packed (vcat)
  short* Bp2  = (short*)alloc(65536 * 2);               // [Wl2|Wr2] packed (hcat)
  int* rp   = (int*)alloc((N_NODES + 1) * 4);
  int* cs   = (int*)alloc((size_t)N_EDGES * 4);
  unsigned* tmp = (unsigned*)alloc((size_t)N_EDGES * 4);
  int* Hc   = (int*)alloc((size_t)NB * NBLK_A * 4);
  int* G    = (int*)alloc((size_t)NB * NBLK_A * 4);
  int* Boff = (int*)alloc((NB + 1) * 4);

  // --- CSR build: two-level counting sort (no global data atomics) ---
  k_bhist<<<NBLK_A, 256, 0, stream>>>(row, Hc);
  k_bscan<<<1, 512, 0, stream>>>(Hc, Boff);
  k_bexp<<<NB, 64, 0, stream>>>(Hc, Boff, G);
  k_bscat<<<NBLK_A, 256, 0, stream>>>(row, col, G, tmp);
  k_bsort<<<NB, 256, 0, stream>>>(tmp, Boff, rp, cs);

  // --- fused weight packing + x conversion (independent of CSR) ---
  k_prep<<<512 + (N_NODES * 32 + 255) / 256, 256, 0, stream>>>(
      x, Wl1, Wr1, Wl2, Wr2, Bp1, Bp2, Acat);

  // --- layer 1 agg ---
  k_agg<false, 128><<<(N_NODES + 3) / 4, 256, 0, stream>>>(
      rp, cs, Acat, Acat, nullptr);

  // --- fused double GEMM: P = relu(Acat@Bp1+bl1)@Bp2 (+bl2 right half) ---
  k_gemm2<<<MT64, 256, 0, stream>>>(Acat, Bp1, bl1, Bp2, bl2, P);

  // --- layer 2 agg + residual -> out ---
  k_agg<true, 0><<<(N_NODES + 3) / 4, 256, 0, stream>>>(
      rp, cs, P, nullptr, out);
}

// Round 15
// 231.196 us; speedup vs baseline: 1.0932x; 1.0932x over previous
//
#include <hip/hip_runtime.h>

#define N_NODES 100000
#define N_EDGES 1600000
#define MPAD    100096   /* 782 * 128 = 1564 * 64 */
#define MT64    1564

#define NB      391      /* ceil(100000/256) buckets of 256 nodes */
#define CH      8192     /* edges per phase-A block */
#define NBLK_A  196      /* ceil(1600000/8192) */

typedef __attribute__((ext_vector_type(8))) short short8;
typedef __attribute__((ext_vector_type(4))) float f32x4;
typedef unsigned int u32;

static __device__ __forceinline__ unsigned short f2bf(float f) {
  unsigned u = __builtin_bit_cast(unsigned, f);
  u += 0x7fffu + ((u >> 16) & 1u);     // round-to-nearest-even
  return (unsigned short)(u >> 16);
}
static __device__ __forceinline__ float bf2f(unsigned short s) {
  unsigned u = ((unsigned)s) << 16;
  return __builtin_bit_cast(float, u);
}

// ---------------- CSR build: two-level LDS counting sort ----------------

__global__ __launch_bounds__(256) void k_bhist(const int* __restrict__ row,
                                               int* __restrict__ Hc) {
  __shared__ int hist[NB];
  int b = blockIdx.x, t = threadIdx.x;
  for (int j = t; j < NB; j += 256) hist[j] = 0;
  __syncthreads();
  int base = b * CH;
  #pragma unroll
  for (int k = 0; k < 8; ++k) {
    int i = base + k * 1024 + t * 4;
    if (i < N_EDGES) {
      int4 r = *(const int4*)(row + i);
      atomicAdd(&hist[r.x >> 8], 1);
      atomicAdd(&hist[r.y >> 8], 1);
      atomicAdd(&hist[r.z >> 8], 1);
      atomicAdd(&hist[r.w >> 8], 1);
    }
  }
  __syncthreads();
  for (int j = t; j < NB; j += 256) Hc[j * NBLK_A + b] = hist[j];
}

__global__ __launch_bounds__(512) void k_bscan(const int* __restrict__ Hc,
                                               int* __restrict__ Boff) {
  int t = threadIdx.x;
  int total = 0;
  if (t < NB) {
    const int* p = Hc + t * NBLK_A;
    for (int i = 0; i < NBLK_A; i += 4) {
      int4 v = *(const int4*)(p + i);
      total += v.x + v.y + v.z + v.w;
    }
  }
  int lane = t & 63, w = t >> 6;
  int incl = total;
  #pragma unroll
  for (int off = 1; off < 64; off <<= 1) {
    int n = __shfl_up(incl, off, 64);
    if (lane >= off) incl += n;
  }
  __shared__ int ws[8];
  if (lane == 63) ws[w] = incl;
  __syncthreads();
  int wo = 0;
  for (int ww = 0; ww < w; ++ww) wo += ws[ww];
  int excl = wo + incl - total;
  if (t < NB) Boff[t] = excl;
  if (t == NB - 1) Boff[NB] = excl + total;
}

__global__ __launch_bounds__(64) void k_bexp(const int* __restrict__ Hc,
                                             const int* __restrict__ Boff,
                                             int* __restrict__ G) {
  int b = blockIdx.x, l = threadIdx.x;
  int run = Boff[b];
  const int* p = Hc + b * NBLK_A;
  for (int c = 0; c < NBLK_A; c += 64) {
    int idx = c + l;
    int v = (idx < NBLK_A) ? p[idx] : 0;
    int incl = v;
    #pragma unroll
    for (int off = 1; off < 64; off <<= 1) {
      int n = __shfl_up(incl, off, 64);
      if (l >= off) incl += n;
    }
    if (idx < NBLK_A) G[b * NBLK_A + idx] = run + incl - v;
    run += __shfl(incl, 63, 64);
  }
}

__global__ __launch_bounds__(256) void k_bscat(const int* __restrict__ row,
                                               const int* __restrict__ col,
                                               const int* __restrict__ G,
                                               unsigned* __restrict__ tmp) {
  __shared__ int cur[NB];
  int b = blockIdx.x, t = threadIdx.x;
  for (int j = t; j < NB; j += 256) cur[j] = G[j * NBLK_A + b];
  __syncthreads();
  int base = b * CH;
  #pragma unroll
  for (int k = 0; k < 8; ++k) {
    int i = base + k * 1024 + t * 4;
    if (i < N_EDGES) {
      int4 r = *(const int4*)(row + i);
      int4 c = *(const int4*)(col + i);
      int p0 = atomicAdd(&cur[r.x >> 8], 1);
      tmp[p0] = (unsigned)c.x | ((unsigned)(r.x & 255) << 24);
      int p1 = atomicAdd(&cur[r.y >> 8], 1);
      tmp[p1] = (unsigned)c.y | ((unsigned)(r.y & 255) << 24);
      int p2 = atomicAdd(&cur[r.z >> 8], 1);
      tmp[p2] = (unsigned)c.z | ((unsigned)(r.z & 255) << 24);
      int p3 = atomicAdd(&cur[r.w >> 8], 1);
      tmp[p3] = (unsigned)c.w | ((unsigned)(r.w & 255) << 24);
    }
  }
}

__global__ __launch_bounds__(256) void k_bsort(const unsigned* __restrict__ tmp,
                                               const int* __restrict__ Boff,
                                               int* __restrict__ rp,
                                               int* __restrict__ cs) {
  __shared__ int hist[256];
  __shared__ int wsum[4];
  int b = blockIdx.x, t = threadIdx.x;
  int s = Boff[b], e = Boff[b + 1];
  hist[t] = 0;
  __syncthreads();
  for (int i = s + t; i < e; i += 256) atomicAdd(&hist[tmp[i] >> 24], 1);
  __syncthreads();
  int v = hist[t];
  int lane = t & 63, w = t >> 6;
  int incl = v;
  #pragma unroll
  for (int off = 1; off < 64; off <<= 1) {
    int n = __shfl_up(incl, off, 64);
    if (lane >= off) incl += n;
  }
  if (lane == 63) wsum[w] = incl;
  __syncthreads();
  int wo = 0;
  for (int ww = 0; ww < w; ++ww) wo += wsum[ww];
  int excl = s + wo + incl - v;
  int node = (b << 8) + t;
  if (node < N_NODES) rp[node] = excl;
  __syncthreads();
  hist[t] = excl;    // reuse as cursor
  __syncthreads();
  for (int i = s + t; i < e; i += 256) {
    unsigned u = tmp[i];
    int pos = atomicAdd(&hist[u >> 24], 1);
    cs[pos] = (int)(u & 0xFFFFFFu);
  }
  if (b == 0 && t == 0) rp[N_NODES] = N_EDGES;
}

// ---------------- prep: weight pack + x f32->bf16 (fused launch) ----------------

__global__ __launch_bounds__(256) void k_prep(const float* __restrict__ x,
                                              const float* __restrict__ Wl1,
                                              const float* __restrict__ Wr1,
                                              const float* __restrict__ Wl2,
                                              const float* __restrict__ Wr2,
                                              short* __restrict__ Bp1,
                                              short* __restrict__ Bp2,
                                              short* __restrict__ Acat) {
  if (blockIdx.x < 512) {
    int id = blockIdx.x * 256 + threadIdx.x;
    bool second = id >= 65536;
    int lid = id & 65535;
    int j = lid & 7;
    int lane = (lid >> 3) & 63;
    int blk = lid >> 9;
    int nb = blk & 15;
    int kk = blk >> 4;
    int k = kk * 32 + (lane >> 4) * 8 + j;
    int c = nb * 16 + (lane & 15);
    float v;
    if (!second) v = (k < 128) ? Wl1[k * 256 + c] : Wr1[(k - 128) * 256 + c];
    else         v = (c < 128) ? Wl2[k * 128 + c] : Wr2[k * 128 + (c - 128)];
    (second ? Bp2 : Bp1)[lid] = (short)f2bf(v);
  } else {
    int id = (blockIdx.x - 512) * 256 + threadIdx.x;
    if (id >= N_NODES * 32) return;
    int node = id >> 5, c4 = id & 31;
    float4 v = *(const float4*)(x + (size_t)node * 128 + c4 * 4);
    uint2 u;
    u.x = (unsigned)f2bf(v.x) | ((unsigned)f2bf(v.y) << 16);
    u.y = (unsigned)f2bf(v.z) | ((unsigned)f2bf(v.w) << 16);
    *(uint2*)(Acat + (size_t)node * 256 + 128 + c4 * 4) = u;
  }
}

// ---------------- aggregation (R7 version: measured 64.4 us) ----------------

template <bool RESID, int GOFF>
__global__ __launch_bounds__(256) void k_agg(const int* __restrict__ rp,
                                             const int* __restrict__ cs,
                                             const short* __restrict__ src,
                                             short* __restrict__ dst_bf,
                                             float* __restrict__ dst_f32) {
  const int t = __builtin_amdgcn_readfirstlane(blockIdx.x * 4 + (threadIdx.x >> 6));
  if (t >= N_NODES) return;
  const int lane = threadIdx.x & 63;
  const int s = rp[t], e = rp[t + 1];
  const int d = e - s;
  float a0 = 0.f, a1 = 0.f;
  const short* gb = src + GOFF + 2 * lane;
  if (d > 0) {
    const int last = e - 1;
    const int rounds = (d + 15) >> 4;
    for (int r = 0; r < rounds; ++r) {
      int base = s + (r << 4);
      unsigned u[16];
      #pragma unroll
      for (int q = 0; q < 16; ++q) {
        int j = base + q;
        j = (j < last) ? j : last;                       // wave-uniform clamp
        u[q] = *(const unsigned*)(gb + (size_t)cs[j] * 256);
      }
      #pragma unroll
      for (int q = 0; q < 16; ++q) {
        a0 += bf2f((unsigned short)u[q]);
        a1 += bf2f((unsigned short)(u[q] >> 16));
      }
    }
    const int over = (rounds << 4) - d;
    if (over) {
      unsigned ul = *(const unsigned*)(gb + (size_t)cs[last] * 256);
      float c = (float)over;
      a0 -= c * bf2f((unsigned short)ul);
      a1 -= c * bf2f((unsigned short)(ul >> 16));
    }
  }
  if (RESID) {
    unsigned r = *(const unsigned*)(src + (size_t)t * 256 + 128 + 2 * lane);
    a0 += bf2f((unsigned short)r);
    a1 += bf2f((unsigned short)(r >> 16));
    float2 o = {a0, a1};
    *(float2*)(dst_f32 + (size_t)t * 128 + 2 * lane) = o;
  } else {
    *(unsigned*)(dst_bf + (size_t)t * 256 + 2 * lane) =
        (unsigned)f2bf(a0) | ((unsigned)f2bf(a1) << 16);
  }
}

// ---------------- fused double-GEMM with global_load_lds A-staging ----------------

// 64-row tile, 256 threads (4 waves, wave = 64-col strip).
// A-tile (64x512B contiguous = 32 KB) staged via 8x global_load_lds(16B):
// LDS dest LINEAR, global SOURCE pre-swizzled per 16B granule
// (c16 ^= row&7); ds_read_b128 applies the same XOR -> 2-way banks = free.
// Then h = relu(A@Bp1+bl1) -> hb LDS (short-swizzle as before);
// P = h@Bp2 (+bl2 right half) -> full-line stores.
__global__ __launch_bounds__(256) void k_gemm2(const short* __restrict__ A,
                                               const short* __restrict__ Bp1,
                                               const float* __restrict__ bl1,
                                               const short* __restrict__ Bp2,
                                               const float* __restrict__ bl2,
                                               short* __restrict__ P) {
  __shared__ short Ab[64 * 256];           // 32 KB staged A
  __shared__ short hb[64 * 256];           // 32 KB h
  const int rt = blockIdx.x;
  const int lane = threadIdx.x & 63;
  const int wave = threadIdx.x >> 6;       // 0..3
  const int colbase = wave * 64;
  const int row0 = rt * 64;
  const int arow = lane & 15;
  const int kgrp = lane >> 4;
  const int ccol = lane & 15;
  const int crow = (lane >> 4) * 4;

  // ---- stage A tile: 2048 granules of 16B, linear dest, swizzled source ----
  {
    const short* Asrc = A + (size_t)row0 * 256;
    #pragma unroll
    for (int i = 0; i < 8; ++i) {
      int g = (i * 4 + wave) * 64 + lane;        // linear LDS granule
      int r = g >> 5, c = g & 31;
      int sg = (r << 5) | (c ^ (r & 7));         // swizzled source granule
      __builtin_amdgcn_global_load_lds(
          (const __attribute__((address_space(1))) u32*)(Asrc + sg * 8),
          (__attribute__((address_space(3))) u32*)(Ab + g * 8), 16, 0, 0);
    }
  }
  __syncthreads();

  f32x4 acc[4][4];
  const f32x4 zero = {0.f, 0.f, 0.f, 0.f};
  #pragma unroll
  for (int a = 0; a < 4; ++a)
    #pragma unroll
    for (int b = 0; b < 4; ++b) acc[a][b] = zero;

  // ---- GEMM1: h = A @ Bp1 (A from LDS) ----
  const short* Bbase1 = Bp1 + (size_t)lane * 8;
  for (int kk = 0; kk < 8; ++kk) {
    short8 af[4], bfr[4];
    #pragma unroll
    for (int mi = 0; mi < 4; ++mi) {
      const int lrow = mi * 16 + arow;
      const int gc = (kk * 4 + kgrp) ^ (lrow & 7);
      af[mi] = *(const short8*)&Ab[(lrow * 32 + gc) * 8];
    }
    #pragma unroll
    for (int ni = 0; ni < 4; ++ni) {
      int nb = wave * 4 + ni;
      bfr[ni] = *(const short8*)(Bbase1 + ((size_t)(kk * 16 + nb) << 9));
    }
    #pragma unroll
    for (int mi = 0; mi < 4; ++mi)
      #pragma unroll
      for (int ni = 0; ni < 4; ++ni)
        acc[mi][ni] = __builtin_amdgcn_mfma_f32_16x16x32_bf16(af[mi], bfr[ni],
                                                              acc[mi][ni], 0, 0, 0);
  }

  // bias + relu -> swizzled LDS bf16
  #pragma unroll
  for (int ni = 0; ni < 4; ++ni) {
    const int colg = colbase + ni * 16 + ccol;
    const float bv = bl1[colg];
    #pragma unroll
    for (int mi = 0; mi < 4; ++mi) {
      #pragma unroll
      for (int j = 0; j < 4; ++j) {
        const int lrow = mi * 16 + crow + j;
        float v = fmaxf(acc[mi][ni][j] + bv, 0.0f);
        hb[(lrow * 256 + colg) ^ ((lrow & 7) << 3)] = (short)f2bf(v);
      }
    }
  }
  __syncthreads();

  // ---- GEMM2: P = h @ Bp2 ----
  #pragma unroll
  for (int a = 0; a < 4; ++a)
    #pragma unroll
    for (int b = 0; b < 4; ++b) acc[a][b] = zero;
  const short* Bbase2 = Bp2 + (size_t)lane * 8;
  for (int kk = 0; kk < 8; ++kk) {
    short8 af[4], bfr[4];
    const int kb = kk * 32 + kgrp * 8;
    #pragma unroll
    for (int mi = 0; mi < 4; ++mi) {
      const int lrow = mi * 16 + arow;
      af[mi] = *(const short8*)&hb[(lrow * 256 + kb) ^ ((lrow & 7) << 3)];
    }
    #pragma unroll
    for (int ni = 0; ni < 4; ++ni) {
      int nb = wave * 4 + ni;
      bfr[ni] = *(const short8*)(Bbase2 + ((size_t)(kk * 16 + nb) << 9));
    }
    #pragma unroll
    for (int mi = 0; mi < 4; ++mi)
      #pragma unroll
      for (int ni = 0; ni < 4; ++ni)
        acc[mi][ni] = __builtin_amdgcn_mfma_f32_16x16x32_bf16(af[mi], bfr[ni],
                                                              acc[mi][ni], 0, 0, 0);
  }
  __syncthreads();   // everyone done reading h before overwrite

  // bias2 (right half only) -> swizzled LDS bf16
  #pragma unroll
  for (int ni = 0; ni < 4; ++ni) {
    const int colg = colbase + ni * 16 + ccol;
    const float bv = (colg < 128) ? 0.f : bl2[colg - 128];
    #pragma unroll
    for (int mi = 0; mi < 4; ++mi) {
      #pragma unroll
      for (int j = 0; j < 4; ++j) {
        const int lrow = mi * 16 + crow + j;
        float v = acc[mi][ni][j] + bv;
        hb[(lrow * 256 + colg) ^ ((lrow & 7) << 3)] = (short)f2bf(v);
      }
    }
  }
  __syncthreads();

  // cooperative full-line store: 32 groups x 8 shorts = one 512 B row
  const int grp = threadIdx.x & 31;
  const int rb = threadIdx.x >> 5;         // 0..7
  #pragma unroll
  for (int pp = 0; pp < 8; ++pp) {
    const int r = pp * 8 + rb;
    uint4 v4 = *(const uint4*)&hb[(r * 256 + grp * 8) ^ ((r & 7) << 3)];
    *(uint4*)(P + (size_t)(row0 + r) * 256 + grp * 8) = v4;
  }
}

extern "C" void kernel_launch(void* const* d_in, const int* in_sizes, int n_in,
                              void* d_out, int out_size, void* d_ws, size_t ws_size,
                              hipStream_t stream) {
  const float* x   = (const float*)d_in[0];
  const int*   row = (const int*)d_in[1];
  const int*   col = (const int*)d_in[2];
  const float* Wl1 = (const float*)d_in[3];
  const float* bl1 = (const float*)d_in[4];
  const float* Wr1 = (const float*)d_in[5];
  const float* Wl2 = (const float*)d_in[6];
  const float* bl2 = (const float*)d_in[7];
  const float* Wr2 = (const float*)d_in[8];
  float* out = (float*)d_out;

  char* w = (char*)d_ws;
  auto alloc = [&](size_t bytes) {
    char* p = w;
    w += (bytes + 255) & ~(size_t)255;
    return p;
  };
  short* Acat = (short*)alloc((size_t)MPAD * 256 * 2);  // [agg_x_bf16 | x_bf16]
  short* P    = (short*)alloc((size_t)MPAD * 256 * 2);  // [h@Wl2 | h@Wr2+bl2], bf16
  short* Bp1  = (short*)alloc(65536 * 2);               // [Wl1;Wr1] packed (vcat)
  short* Bp2  = (short*)alloc(65536 * 2);               // [Wl2|Wr2] packed (hcat)
  int* rp   = (int*)alloc((N_NODES + 1) * 4);
  int* cs   = (int*)alloc((size_t)N_EDGES * 4);
  unsigned* tmp = (unsigned*)alloc((size_t)N_EDGES * 4);
  int* Hc   = (int*)alloc((size_t)NB * NBLK_A * 4);
  int* G    = (int*)alloc((size_t)NB * NBLK_A * 4);
  int* Boff = (int*)alloc((NB + 1) * 4);

  // --- CSR build: two-level counting sort (no global data atomics) ---
  k_bhist<<<NBLK_A, 256, 0, stream>>>(row, Hc);
  k_bscan<<<1, 512, 0, stream>>>(Hc, Boff);
  k_bexp<<<NB, 64, 0, stream>>>(Hc, Boff, G);
  k_bscat<<<NBLK_A, 256, 0, stream>>>(row, col, G, tmp);
  k_bsort<<<NB, 256, 0, stream>>>(tmp, Boff, rp, cs);

  // --- fused weight packing + x conversion (independent of CSR) ---
  k_prep<<<512 + (N_NODES * 32 + 255) / 256, 256, 0, stream>>>(
      x, Wl1, Wr1, Wl2, Wr2, Bp1, Bp2, Acat);

  // --- layer 1 agg ---
  k_agg<false, 128><<<(N_NODES + 3) / 4, 256, 0, stream>>>(
      rp, cs, Acat, Acat, nullptr);

  // --- fused double GEMM: P = relu(Acat@Bp1+bl1)@Bp2 (+bl2 right half) ---
  k_gemm2<<<MT64, 256, 0, stream>>>(Acat, Bp1, bl1, Bp2, bl2, P);

  // --- layer 2 agg + residual -> out ---
  k_agg<true, 0><<<(N_NODES + 3) / 4, 256, 0, stream>>>(
      rp, cs, P, nullptr, out);
}

// Round 16
// 224.884 us; speedup vs baseline: 1.1238x; 1.0281x over previous
//
#include <hip/hip_runtime.h>

#define N_NODES 100000
#define N_EDGES 1600000
#define MPAD    100096   /* 782 * 128 = 1564 * 64 */
#define MT64    1564

#define NB      391      /* ceil(100000/256) buckets of 256 nodes */
#define CH      8192     /* edges per phase-A block */
#define NBLK_A  196      /* ceil(1600000/8192) */

typedef __attribute__((ext_vector_type(8))) short short8;
typedef __attribute__((ext_vector_type(4))) float f32x4;
typedef unsigned int u32;

static __device__ __forceinline__ unsigned short f2bf(float f) {
  unsigned u = __builtin_bit_cast(unsigned, f);
  u += 0x7fffu + ((u >> 16) & 1u);     // round-to-nearest-even
  return (unsigned short)(u >> 16);
}
static __device__ __forceinline__ float bf2f(unsigned short s) {
  unsigned u = ((unsigned)s) << 16;
  return __builtin_bit_cast(float, u);
}

// ---------------- CSR build: two-level LDS counting sort ----------------

__global__ __launch_bounds__(256) void k_bhist(const int* __restrict__ row,
                                               int* __restrict__ Hc) {
  __shared__ int hist[NB];
  int b = blockIdx.x, t = threadIdx.x;
  for (int j = t; j < NB; j += 256) hist[j] = 0;
  __syncthreads();
  int base = b * CH;
  #pragma unroll
  for (int k = 0; k < 8; ++k) {
    int i = base + k * 1024 + t * 4;
    if (i < N_EDGES) {
      int4 r = *(const int4*)(row + i);
      atomicAdd(&hist[r.x >> 8], 1);
      atomicAdd(&hist[r.y >> 8], 1);
      atomicAdd(&hist[r.z >> 8], 1);
      atomicAdd(&hist[r.w >> 8], 1);
    }
  }
  __syncthreads();
  for (int j = t; j < NB; j += 256) Hc[j * NBLK_A + b] = hist[j];
}

__global__ __launch_bounds__(512) void k_bscan(const int* __restrict__ Hc,
                                               int* __restrict__ Boff) {
  int t = threadIdx.x;
  int total = 0;
  if (t < NB) {
    const int* p = Hc + t * NBLK_A;
    for (int i = 0; i < NBLK_A; i += 4) {
      int4 v = *(const int4*)(p + i);
      total += v.x + v.y + v.z + v.w;
    }
  }
  int lane = t & 63, w = t >> 6;
  int incl = total;
  #pragma unroll
  for (int off = 1; off < 64; off <<= 1) {
    int n = __shfl_up(incl, off, 64);
    if (lane >= off) incl += n;
  }
  __shared__ int ws[8];
  if (lane == 63) ws[w] = incl;
  __syncthreads();
  int wo = 0;
  for (int ww = 0; ww < w; ++ww) wo += ws[ww];
  int excl = wo + incl - total;
  if (t < NB) Boff[t] = excl;
  if (t == NB - 1) Boff[NB] = excl + total;
}

__global__ __launch_bounds__(64) void k_bexp(const int* __restrict__ Hc,
                                             const int* __restrict__ Boff,
                                             int* __restrict__ G) {
  int b = blockIdx.x, l = threadIdx.x;
  int run = Boff[b];
  const int* p = Hc + b * NBLK_A;
  for (int c = 0; c < NBLK_A; c += 64) {
    int idx = c + l;
    int v = (idx < NBLK_A) ? p[idx] : 0;
    int incl = v;
    #pragma unroll
    for (int off = 1; off < 64; off <<= 1) {
      int n = __shfl_up(incl, off, 64);
      if (l >= off) incl += n;
    }
    if (idx < NBLK_A) G[b * NBLK_A + idx] = run + incl - v;
    run += __shfl(incl, 63, 64);
  }
}

__global__ __launch_bounds__(256) void k_bscat(const int* __restrict__ row,
                                               const int* __restrict__ col,
                                               const int* __restrict__ G,
                                               unsigned* __restrict__ tmp) {
  __shared__ int cur[NB];
  int b = blockIdx.x, t = threadIdx.x;
  for (int j = t; j < NB; j += 256) cur[j] = G[j * NBLK_A + b];
  __syncthreads();
  int base = b * CH;
  #pragma unroll
  for (int k = 0; k < 8; ++k) {
    int i = base + k * 1024 + t * 4;
    if (i < N_EDGES) {
      int4 r = *(const int4*)(row + i);
      int4 c = *(const int4*)(col + i);
      int p0 = atomicAdd(&cur[r.x >> 8], 1);
      tmp[p0] = (unsigned)c.x | ((unsigned)(r.x & 255) << 24);
      int p1 = atomicAdd(&cur[r.y >> 8], 1);
      tmp[p1] = (unsigned)c.y | ((unsigned)(r.y & 255) << 24);
      int p2 = atomicAdd(&cur[r.z >> 8], 1);
      tmp[p2] = (unsigned)c.z | ((unsigned)(r.z & 255) << 24);
      int p3 = atomicAdd(&cur[r.w >> 8], 1);
      tmp[p3] = (unsigned)c.w | ((unsigned)(r.w & 255) << 24);
    }
  }
}

__global__ __launch_bounds__(256) void k_bsort(const unsigned* __restrict__ tmp,
                                               const int* __restrict__ Boff,
                                               int* __restrict__ rp,
                                               int* __restrict__ cs) {
  __shared__ int hist[256];
  __shared__ int wsum[4];
  int b = blockIdx.x, t = threadIdx.x;
  int s = Boff[b], e = Boff[b + 1];
  hist[t] = 0;
  __syncthreads();
  for (int i = s + t; i < e; i += 256) atomicAdd(&hist[tmp[i] >> 24], 1);
  __syncthreads();
  int v = hist[t];
  int lane = t & 63, w = t >> 6;
  int incl = v;
  #pragma unroll
  for (int off = 1; off < 64; off <<= 1) {
    int n = __shfl_up(incl, off, 64);
    if (lane >= off) incl += n;
  }
  if (lane == 63) wsum[w] = incl;
  __syncthreads();
  int wo = 0;
  for (int ww = 0; ww < w; ++ww) wo += wsum[ww];
  int excl = s + wo + incl - v;
  int node = (b << 8) + t;
  if (node < N_NODES) rp[node] = excl;
  __syncthreads();
  hist[t] = excl;    // reuse as cursor
  __syncthreads();
  for (int i = s + t; i < e; i += 256) {
    unsigned u = tmp[i];
    int pos = atomicAdd(&hist[u >> 24], 1);
    cs[pos] = (int)(u & 0xFFFFFFu);
  }
  if (b == 0 && t == 0) rp[N_NODES] = N_EDGES;
}

// ---------------- prep: weight pack + x f32->bf16 (fused launch) ----------------

__global__ __launch_bounds__(256) void k_prep(const float* __restrict__ x,
                                              const float* __restrict__ Wl1,
                                              const float* __restrict__ Wr1,
                                              const float* __restrict__ Wl2,
                                              const float* __restrict__ Wr2,
                                              short* __restrict__ Bp1,
                                              short* __restrict__ Bp2,
                                              short* __restrict__ Acat) {
  if (blockIdx.x < 512) {
    int id = blockIdx.x * 256 + threadIdx.x;
    bool second = id >= 65536;
    int lid = id & 65535;
    int j = lid & 7;
    int lane = (lid >> 3) & 63;
    int blk = lid >> 9;
    int nb = blk & 15;
    int kk = blk >> 4;
    int k = kk * 32 + (lane >> 4) * 8 + j;
    int c = nb * 16 + (lane & 15);
    float v;
    if (!second) v = (k < 128) ? Wl1[k * 256 + c] : Wr1[(k - 128) * 256 + c];
    else         v = (c < 128) ? Wl2[k * 128 + c] : Wr2[k * 128 + (c - 128)];
    (second ? Bp2 : Bp1)[lid] = (short)f2bf(v);
  } else {
    int id = (blockIdx.x - 512) * 256 + threadIdx.x;
    if (id >= N_NODES * 32) return;
    int node = id >> 5, c4 = id & 31;
    float4 v = *(const float4*)(x + (size_t)node * 128 + c4 * 4);
    uint2 u;
    u.x = (unsigned)f2bf(v.x) | ((unsigned)f2bf(v.y) << 16);
    u.y = (unsigned)f2bf(v.z) | ((unsigned)f2bf(v.w) << 16);
    *(uint2*)(Acat + (size_t)node * 256 + 128 + c4 * 4) = u;
  }
}

// ---------------- aggregation (R7 version: measured 64.4 us) ----------------

template <bool RESID, int GOFF>
__global__ __launch_bounds__(256) void k_agg(const int* __restrict__ rp,
                                             const int* __restrict__ cs,
                                             const short* __restrict__ src,
                                             short* __restrict__ dst_bf,
                                             float* __restrict__ dst_f32) {
  const int t = __builtin_amdgcn_readfirstlane(blockIdx.x * 4 + (threadIdx.x >> 6));
  if (t >= N_NODES) return;
  const int lane = threadIdx.x & 63;
  const int s = rp[t], e = rp[t + 1];
  const int d = e - s;
  float a0 = 0.f, a1 = 0.f;
  const short* gb = src + GOFF + 2 * lane;
  if (d > 0) {
    const int last = e - 1;
    const int rounds = (d + 15) >> 4;
    for (int r = 0; r < rounds; ++r) {
      int base = s + (r << 4);
      unsigned u[16];
      #pragma unroll
      for (int q = 0; q < 16; ++q) {
        int j = base + q;
        j = (j < last) ? j : last;                       // wave-uniform clamp
        u[q] = *(const unsigned*)(gb + (size_t)cs[j] * 256);
      }
      #pragma unroll
      for (int q = 0; q < 16; ++q) {
        a0 += bf2f((unsigned short)u[q]);
        a1 += bf2f((unsigned short)(u[q] >> 16));
      }
    }
    const int over = (rounds << 4) - d;
    if (over) {
      unsigned ul = *(const unsigned*)(gb + (size_t)cs[last] * 256);
      float c = (float)over;
      a0 -= c * bf2f((unsigned short)ul);
      a1 -= c * bf2f((unsigned short)(ul >> 16));
    }
  }
  if (RESID) {
    unsigned r = *(const unsigned*)(src + (size_t)t * 256 + 128 + 2 * lane);
    a0 += bf2f((unsigned short)r);
    a1 += bf2f((unsigned short)(r >> 16));
    float2 o = {a0, a1};
    *(float2*)(dst_f32 + (size_t)t * 128 + 2 * lane) = o;
  } else {
    *(unsigned*)(dst_bf + (size_t)t * 256 + 2 * lane) =
        (unsigned)f2bf(a0) | ((unsigned)f2bf(a1) << 16);
  }
}

// ---------------- fused double-GEMM: single 32 KB LDS buffer (A -> h -> P) ----------------

// 64-row tile, 256 threads (4 waves, wave = 64-col strip).
// A-tile staged via 8x global_load_lds(16B): LDS dest LINEAR, global SOURCE
// pre-swizzled per 16B granule (c16 ^= row&7); ds_read applies the same XOR.
// A is fully consumed by GEMM1, so ONE 32 KB buffer is reused A -> h -> P
// (extra barrier between last A-read and first h-write). 32 KB LDS +
// launch_bounds(256,3) -> 3 blocks/CU: other blocks' MFMA covers barriers.
// kk loops unroll x2 to pair B-load latency windows.
__global__ __launch_bounds__(256, 3) void k_gemm2(const short* __restrict__ A,
                                                  const short* __restrict__ Bp1,
                                                  const float* __restrict__ bl1,
                                                  const short* __restrict__ Bp2,
                                                  const float* __restrict__ bl2,
                                                  short* __restrict__ P) {
  __shared__ short buf[64 * 256];          // 32 KB, reused A -> h -> P
  const int rt = blockIdx.x;
  const int lane = threadIdx.x & 63;
  const int wave = threadIdx.x >> 6;       // 0..3
  const int colbase = wave * 64;
  const int row0 = rt * 64;
  const int arow = lane & 15;
  const int kgrp = lane >> 4;
  const int ccol = lane & 15;
  const int crow = (lane >> 4) * 4;

  // ---- stage A tile: 2048 granules of 16B, linear dest, swizzled source ----
  {
    const short* Asrc = A + (size_t)row0 * 256;
    #pragma unroll
    for (int i = 0; i < 8; ++i) {
      int g = (i * 4 + wave) * 64 + lane;        // linear LDS granule
      int r = g >> 5, c = g & 31;
      int sg = (r << 5) | (c ^ (r & 7));         // swizzled source granule
      __builtin_amdgcn_global_load_lds(
          (const __attribute__((address_space(1))) u32*)(Asrc + sg * 8),
          (__attribute__((address_space(3))) u32*)(buf + g * 8), 16, 0, 0);
    }
  }
  __syncthreads();

  f32x4 acc[4][4];
  const f32x4 zero = {0.f, 0.f, 0.f, 0.f};
  #pragma unroll
  for (int a = 0; a < 4; ++a)
    #pragma unroll
    for (int b = 0; b < 4; ++b) acc[a][b] = zero;

  // ---- GEMM1: h = A @ Bp1 (A from LDS) ----
  const short* Bbase1 = Bp1 + (size_t)lane * 8;
  #pragma unroll 2
  for (int kk = 0; kk < 8; ++kk) {
    short8 af[4], bfr[4];
    #pragma unroll
    for (int mi = 0; mi < 4; ++mi) {
      const int lrow = mi * 16 + arow;
      const int gc = (kk * 4 + kgrp) ^ (lrow & 7);
      af[mi] = *(const short8*)&buf[(lrow * 32 + gc) * 8];
    }
    #pragma unroll
    for (int ni = 0; ni < 4; ++ni) {
      int nb = wave * 4 + ni;
      bfr[ni] = *(const short8*)(Bbase1 + ((size_t)(kk * 16 + nb) << 9));
    }
    #pragma unroll
    for (int mi = 0; mi < 4; ++mi)
      #pragma unroll
      for (int ni = 0; ni < 4; ++ni)
        acc[mi][ni] = __builtin_amdgcn_mfma_f32_16x16x32_bf16(af[mi], bfr[ni],
                                                              acc[mi][ni], 0, 0, 0);
  }
  __syncthreads();   // all waves done reading A before h overwrites buf

  // bias + relu -> swizzled LDS bf16 (h into buf)
  #pragma unroll
  for (int ni = 0; ni < 4; ++ni) {
    const int colg = colbase + ni * 16 + ccol;
    const float bv = bl1[colg];
    #pragma unroll
    for (int mi = 0; mi < 4; ++mi) {
      #pragma unroll
      for (int j = 0; j < 4; ++j) {
        const int lrow = mi * 16 + crow + j;
        float v = fmaxf(acc[mi][ni][j] + bv, 0.0f);
        buf[(lrow * 256 + colg) ^ ((lrow & 7) << 3)] = (short)f2bf(v);
      }
    }
  }
  __syncthreads();

  // ---- GEMM2: P = h @ Bp2 ----
  #pragma unroll
  for (int a = 0; a < 4; ++a)
    #pragma unroll
    for (int b = 0; b < 4; ++b) acc[a][b] = zero;
  const short* Bbase2 = Bp2 + (size_t)lane * 8;
  #pragma unroll 2
  for (int kk = 0; kk < 8; ++kk) {
    short8 af[4], bfr[4];
    const int kb = kk * 32 + kgrp * 8;
    #pragma unroll
    for (int mi = 0; mi < 4; ++mi) {
      const int lrow = mi * 16 + arow;
      af[mi] = *(const short8*)&buf[(lrow * 256 + kb) ^ ((lrow & 7) << 3)];
    }
    #pragma unroll
    for (int ni = 0; ni < 4; ++ni) {
      int nb = wave * 4 + ni;
      bfr[ni] = *(const short8*)(Bbase2 + ((size_t)(kk * 16 + nb) << 9));
    }
    #pragma unroll
    for (int mi = 0; mi < 4; ++mi)
      #pragma unroll
      for (int ni = 0; ni < 4; ++ni)
        acc[mi][ni] = __builtin_amdgcn_mfma_f32_16x16x32_bf16(af[mi], bfr[ni],
                                                              acc[mi][ni], 0, 0, 0);
  }
  __syncthreads();   // everyone done reading h before P overwrites buf

  // bias2 (right half only) -> swizzled LDS bf16 (P into buf)
  #pragma unroll
  for (int ni = 0; ni < 4; ++ni) {
    const int colg = colbase + ni * 16 + ccol;
    const float bv = (colg < 128) ? 0.f : bl2[colg - 128];
    #pragma unroll
    for (int mi = 0; mi < 4; ++mi) {
      #pragma unroll
      for (int j = 0; j < 4; ++j) {
        const int lrow = mi * 16 + crow + j;
        float v = acc[mi][ni][j] + bv;
        buf[(lrow * 256 + colg) ^ ((lrow & 7) << 3)] = (short)f2bf(v);
      }
    }
  }
  __syncthreads();

  // cooperative full-line store: 32 groups x 8 shorts = one 512 B row
  const int grp = threadIdx.x & 31;
  const int rb = threadIdx.x >> 5;         // 0..7
  #pragma unroll
  for (int pp = 0; pp < 8; ++pp) {
    const int r = pp * 8 + rb;
    uint4 v4 = *(const uint4*)&buf[(r * 256 + grp * 8) ^ ((r & 7) << 3)];
    *(uint4*)(P + (size_t)(row0 + r) * 256 + grp * 8) = v4;
  }
}

extern "C" void kernel_launch(void* const* d_in, const int* in_sizes, int n_in,
                              void* d_out, int out_size, void* d_ws, size_t ws_size,
                              hipStream_t stream) {
  const float* x   = (const float*)d_in[0];
  const int*   row = (const int*)d_in[1];
  const int*   col = (const int*)d_in[2];
  const float* Wl1 = (const float*)d_in[3];
  const float* bl1 = (const float*)d_in[4];
  const float* Wr1 = (const float*)d_in[5];
  const float* Wl2 = (const float*)d_in[6];
  const float* bl2 = (const float*)d_in[7];
  const float* Wr2 = (const float*)d_in[8];
  float* out = (float*)d_out;

  char* w = (char*)d_ws;
  auto alloc = [&](size_t bytes) {
    char* p = w;
    w += (bytes + 255) & ~(size_t)255;
    return p;
  };
  short* Acat = (short*)alloc((size_t)MPAD * 256 * 2);  // [agg_x_bf16 | x_bf16]
  short* P    = (short*)alloc((size_t)MPAD * 256 * 2);  // [h@Wl2 | h@Wr2+bl2], bf16
  short* Bp1  = (short*)alloc(65536 * 2);               // [Wl1;Wr1] packed (vcat)
  short* Bp2  = (short*)alloc(65536 * 2);               // [Wl2|Wr2] packed (hcat)
  int* rp   = (int*)alloc((N_NODES + 1) * 4);
  int* cs   = (int*)alloc((size_t)N_EDGES * 4);
  unsigned* tmp = (unsigned*)alloc((size_t)N_EDGES * 4);
  int* Hc   = (int*)alloc((size_t)NB * NBLK_A * 4);
  int* G    = (int*)alloc((size_t)NB * NBLK_A * 4);
  int* Boff = (int*)alloc((NB + 1) * 4);

  // --- CSR build: two-level counting sort (no global data atomics) ---
  k_bhist<<<NBLK_A, 256, 0, stream>>>(row, Hc);
  k_bscan<<<1, 512, 0, stream>>>(Hc, Boff);
  k_bexp<<<NB, 64, 0, stream>>>(Hc, Boff, G);
  k_bscat<<<NBLK_A, 256, 0, stream>>>(row, col, G, tmp);
  k_bsort<<<NB, 256, 0, stream>>>(tmp, Boff, rp, cs);

  // --- fused weight packing + x conversion (independent of CSR) ---
  k_prep<<<512 + (N_NODES * 32 + 255) / 256, 256, 0, stream>>>(
      x, Wl1, Wr1, Wl2, Wr2, Bp1, Bp2, Acat);

  // --- layer 1 agg ---
  k_agg<false, 128><<<(N_NODES + 3) / 4, 256, 0, stream>>>(
      rp, cs, Acat, Acat, nullptr);

  // --- fused double GEMM: P = relu(Acat@Bp1+bl1)@Bp2 (+bl2 right half) ---
  k_gemm2<<<MT64, 256, 0, stream>>>(Acat, Bp1, bl1, Bp2, bl2, P);

  // --- layer 2 agg + residual -> out ---
  k_agg<true, 0><<<(N_NODES + 3) / 4, 256, 0, stream>>>(
      rp, cs, P, nullptr, out);
}